// Round 10
// baseline (805.507 us; speedup 1.0000x reference)
//
#include <hip/hip_runtime.h>
#include <hip/hip_bf16.h>

#define HIDC 2048
#define NHEADS 16
#define HDIM 128
#define NB 4
#define NS 4096
#define NROWS (NB*NS)
#define QSTR 6144
#define EPSV 1e-6f

typedef __attribute__((ext_vector_type(8))) short s16x8;
typedef __attribute__((ext_vector_type(4))) float f32x4;
typedef __attribute__((ext_vector_type(8))) unsigned short u16x8;

static __device__ __forceinline__ unsigned short f2b(float f) {
  unsigned int u = __float_as_uint(f);
  u += 0x7fffu + ((u >> 16) & 1u);
  return (unsigned short)(u >> 16);
}
static __device__ __forceinline__ float b2f(unsigned short h) {
  return __uint_as_float(((unsigned int)h) << 16);
}

static __device__ __forceinline__ void gload_lds16(const unsigned short* g, unsigned short* l) {
  __builtin_amdgcn_global_load_lds(
      (const __attribute__((address_space(1))) void*)g,
      (__attribute__((address_space(3))) void*)l, 16, 0, 0);
}

// fp32 -> bf16 conversion for hs (16384 blocks) + 4 weights (2048 blocks each)
__global__ __launch_bounds__(256) void convert_all(
    const float* __restrict__ hs, const float* __restrict__ qw,
    const float* __restrict__ kw, const float* __restrict__ vw,
    const float* __restrict__ ow,
    unsigned short* __restrict__ hsb, unsigned short* __restrict__ qwb,
    unsigned short* __restrict__ kwb, unsigned short* __restrict__ vwb,
    unsigned short* __restrict__ owb)
{
  int bid = blockIdx.x;
  const float* src; unsigned short* dst; size_t base;
  if (bid < 16384) { src = hs; dst = hsb; base = (size_t)bid << 11; }
  else {
    int t = bid - 16384; int wsel = t >> 11; int wb = t & 2047;
    src = wsel == 0 ? qw : wsel == 1 ? kw : wsel == 2 ? vw : ow;
    dst = wsel == 0 ? qwb : wsel == 1 ? kwb : wsel == 2 ? vwb : owb;
    base = (size_t)wb << 11;
  }
  size_t i = base + ((size_t)threadIdx.x << 3);
  float4 a = *(const float4*)(src + i);
  float4 b = *(const float4*)(src + i + 4);
  u16x8 o;
  o[0] = f2b(a.x); o[1] = f2b(a.y); o[2] = f2b(a.z); o[3] = f2b(a.w);
  o[4] = f2b(b.x); o[5] = f2b(b.y); o[6] = f2b(b.z); o[7] = f2b(b.w);
  *(u16x8*)(dst + i) = o;
}

// 256x128-tile bf16 GEMM, 4 waves (2Mx2N, per-wave 128x64), BK=32, ring-3 LDS
// slots (72 KiB), 2 blocks/CU for cross-block MFMA/LDS overlap (m114 mechanism:
// one block's read/barrier epoch hides under the other block's MFMA epoch).
// Step: gate vmcnt | bar | 12 ds_read (bfr,af) | stage slot s+2 (6 gloads) |
//       sched_bar | 32 MFMA (compiler-counted lgkm waits) | rotate ring.
// Safety: gate(6) at step s => stage(s-1) landed => slot s+1 resident at s+1;
// stage at s targets slot read at s-1, whose reads lgkm-drained before that
// wave's MFMA(s-1), which precedes BAR(s). XOR-swizzled LDS (0 conflicts).
template<int QKV, int OUT_BF16>
__global__ __launch_bounds__(256, 2) void gemm256(
    const unsigned short* __restrict__ A,
    const unsigned short* __restrict__ B0,
    const unsigned short* __restrict__ B1,
    const unsigned short* __restrict__ B2,
    const float* __restrict__ bias0,
    const float* __restrict__ bias1,
    const float* __restrict__ bias2,
    void* __restrict__ Cp,
    int ntile, int astr, int ostr)
{
  __shared__ unsigned short lds[36864];   // 72 KiB: 3 slots x [A:8192][B:4096] ushorts
  const int tid = threadIdx.x;
  const int lane = tid & 63, wid = tid >> 6;       // 4 waves
  const int wr = wid >> 1, wc = wid & 1;           // 2M x 2N
  const int l15 = lane & 15, l4 = lane >> 4;

  // bijective XCD swizzle (grid % 8 == 0) + L2 chunking: 4 bm x all bn
  const int cpx = (int)gridDim.x >> 3;
  const int bidx = (int)blockIdx.x;
  const int wg = (bidx & 7) * cpx + (bidx >> 3);
  const int csz = ntile << 2;
  const int chunk = wg / csz;
  const int t = wg % csz;
  const int bm = ((chunk << 2) + (t & 3)) << 8;    // 256-row tiles
  const int bn = (t >> 2) << 7;                    // 128-col tiles

  const unsigned short* Bp = B0;
  const float* bias = bias0;
  bool act = false;
  int bnw = bn;
  if (QKV) {
    int seg = bn >> 11;
    Bp = seg == 0 ? B0 : (seg == 1 ? B1 : B2);
    bias = seg == 0 ? bias0 : (seg == 1 ? bias1 : bias2);
    act = seg < 2;
    bnw = bn & 2047;
  }

  // staging: A = 16 chunks (16rows x 32cols, 1KB), wave stages chunks 4w..4w+3;
  // B = 8 chunks, wave stages 2w..2w+1. Source col inverse-swizzled.
  const int srow = lane >> 2;
  const int scol = (((lane & 3) ^ ((srow >> 1) & 3)) << 3);
  const unsigned short* Asrc0 = A + (size_t)(bm + ((wid << 2) << 4) + srow) * astr + scol;
  const unsigned short* Asrc1 = Asrc0 + (size_t)16 * astr;
  const unsigned short* Asrc2 = Asrc0 + (size_t)32 * astr;
  const unsigned short* Asrc3 = Asrc0 + (size_t)48 * astr;
  const unsigned short* Bsrc0 = Bp + (size_t)(bnw + ((wid << 1) << 4) + srow) * HIDC + scol;
  const unsigned short* Bsrc1 = Bsrc0 + (size_t)16 * HIDC;
  const int adst = wid << 11;              // A chunk dest base (ushorts)
  const int bdst = 8192 + (wid << 10);     // B chunk dest base

  // fragment read offsets (swizzled): row*32 + ((l4 ^ ((row>>1)&3))<<3)
  const int xa = ((l4 ^ ((l15 >> 1) & 3)) << 3);
  const int abase = ((wr << 7) + l15) * 32 + xa;
  const int bbase = 8192 + ((wc << 6) + l15) * 32 + xa;

  f32x4 acc[8][4] = {};
  s16x8 af[8], bfr[4];

#define STAGE6(sb_, kt_) { \
    gload_lds16(Asrc0 + (kt_), &lds[(sb_) + adst]); \
    gload_lds16(Asrc1 + (kt_), &lds[(sb_) + adst + 512]); \
    gload_lds16(Asrc2 + (kt_), &lds[(sb_) + adst + 1024]); \
    gload_lds16(Asrc3 + (kt_), &lds[(sb_) + adst + 1536]); \
    gload_lds16(Bsrc0 + (kt_), &lds[(sb_) + bdst]); \
    gload_lds16(Bsrc1 + (kt_), &lds[(sb_) + bdst + 512]); }

#define MMROW(mf_) { \
    acc[mf_][0] = __builtin_amdgcn_mfma_f32_16x16x32_bf16(af[mf_], bfr[0], acc[mf_][0], 0, 0, 0); \
    acc[mf_][1] = __builtin_amdgcn_mfma_f32_16x16x32_bf16(af[mf_], bfr[1], acc[mf_][1], 0, 0, 0); \
    acc[mf_][2] = __builtin_amdgcn_mfma_f32_16x16x32_bf16(af[mf_], bfr[2], acc[mf_][2], 0, 0, 0); \
    acc[mf_][3] = __builtin_amdgcn_mfma_f32_16x16x32_bf16(af[mf_], bfr[3], acc[mf_][3], 0, 0, 0); }

#define DO_STEP(GATE, STG, KT) { \
    if ((GATE) == 6)      { asm volatile("s_waitcnt vmcnt(6)" ::: "memory"); } \
    else if ((GATE) == 0) { asm volatile("s_waitcnt vmcnt(0)" ::: "memory"); } \
    __builtin_amdgcn_s_barrier(); \
    bfr[0] = *(const s16x8*)&lds[rb + bbase]; \
    bfr[1] = *(const s16x8*)&lds[rb + bbase + 512]; \
    bfr[2] = *(const s16x8*)&lds[rb + bbase + 1024]; \
    bfr[3] = *(const s16x8*)&lds[rb + bbase + 1536]; \
    af[0] = *(const s16x8*)&lds[rb + abase]; \
    af[1] = *(const s16x8*)&lds[rb + abase + 512]; \
    af[2] = *(const s16x8*)&lds[rb + abase + 1024]; \
    af[3] = *(const s16x8*)&lds[rb + abase + 1536]; \
    af[4] = *(const s16x8*)&lds[rb + abase + 2048]; \
    af[5] = *(const s16x8*)&lds[rb + abase + 2560]; \
    af[6] = *(const s16x8*)&lds[rb + abase + 3072]; \
    af[7] = *(const s16x8*)&lds[rb + abase + 3584]; \
    if (STG) STAGE6(sb, KT); \
    __builtin_amdgcn_sched_barrier(0); \
    __builtin_amdgcn_s_setprio(1); \
    MMROW(0) MMROW(1) MMROW(2) MMROW(3) \
    MMROW(4) MMROW(5) MMROW(6) MMROW(7) \
    __builtin_amdgcn_s_setprio(0); \
    { int t_ = rb; rb = (rb == 24576) ? 0 : rb + 12288; sb = t_; } \
  }

  // prologue: stage slots 0 (kt=0) and 1 (kt=32); first step gates vmcnt(6)
  STAGE6(0, 0);
  STAGE6(12288, 32);
  int rb = 0, sb = 24576;

  for (int s = 0; s < 62; ++s) {
    DO_STEP(6, 1, (s + 2) << 5)
  }
  DO_STEP(0, 0, 0)
  DO_STEP(-1, 0, 0)

#undef DO_STEP
#undef MMROW
#undef STAGE6

  #pragma unroll
  for (int nf = 0; nf < 4; ++nf) {
    const int colw = (wc << 6) + (nf << 4) + l15;
    const float bv = bias[bnw + colw];
    #pragma unroll
    for (int mf = 0; mf < 8; ++mf) {
      #pragma unroll
      for (int r = 0; r < 4; ++r) {
        const int row = bm + (wr << 7) + (mf << 4) + (l4 << 2) + r;
        float v = acc[mf][nf][r] + bv;
        if (QKV) { if (act) v = (v > 0.f) ? (v + 1.f) : __expf(v); }
        const size_t off = (size_t)row * ostr + bn + colw;
        if (OUT_BF16) ((unsigned short*)Cp)[off] = f2b(v);
        else          ((float*)Cp)[off] = v;
      }
    }
  }
}

// kv partials over 16 S-chunks (deterministic, no atomics). 1024 blocks -> 4/CU.
__global__ __launch_bounds__(256) void kv_partial(
    const unsigned short* __restrict__ kp, const unsigned short* __restrict__ vv,
    float* __restrict__ kvp, float* __restrict__ ksp)
{
  const int bh = blockIdx.x >> 4;
  const int chunk = blockIdx.x & 15;
  const int b = bh >> 4, h = bh & 15;
  const int tid = threadIdx.x;
  const int td = tid >> 4, te = tid & 15;

  __shared__ float kpl[32][128];
  __shared__ float vl[32][132];

  float acc[8][8] = {};
  float ks[8] = {};

  const size_t rowbase = (size_t)b * NS * QSTR + (size_t)h * HDIM;
  const int s0 = chunk * 256;

  for (int st = 0; st < 256; st += 32) {
    __syncthreads();
    #pragma unroll
    for (int i = 0; i < 2; ++i) {
      int idx = tid + (i << 8);
      int row = idx >> 4, q = idx & 15;
      size_t g = rowbase + (size_t)(s0 + st + row) * QSTR + (q << 3);
      u16x8 k8 = *(const u16x8*)(kp + g);
      u16x8 v8 = *(const u16x8*)(vv + g);
      float tk[8], tv[8];
      #pragma unroll
      for (int j = 0; j < 8; ++j) { tk[j] = b2f(k8[j]); tv[j] = b2f(v8[j]); }
      *(float4*)&kpl[row][(q << 3)]     = make_float4(tk[0], tk[1], tk[2], tk[3]);
      *(float4*)&kpl[row][(q << 3) + 4] = make_float4(tk[4], tk[5], tk[6], tk[7]);
      *(float4*)&vl[row][(q << 3)]      = make_float4(tv[0], tv[1], tv[2], tv[3]);
      *(float4*)&vl[row][(q << 3) + 4]  = make_float4(tv[4], tv[5], tv[6], tv[7]);
    }
    __syncthreads();
    #pragma unroll 4
    for (int s = 0; s < 32; ++s) {
      float kd[8], ve[8];
      *(float4*)&kd[0] = *(const float4*)&kpl[s][td << 3];
      *(float4*)&kd[4] = *(const float4*)&kpl[s][(td << 3) + 4];
      *(float4*)&ve[0] = *(const float4*)&vl[s][te << 3];
      *(float4*)&ve[4] = *(const float4*)&vl[s][(te << 3) + 4];
      if (te == 0) {
        #pragma unroll
        for (int i = 0; i < 8; ++i) ks[i] += kd[i];
      }
      #pragma unroll
      for (int i = 0; i < 8; ++i)
        #pragma unroll
        for (int j = 0; j < 8; ++j)
          acc[i][j] += kd[i] * ve[j];
    }
  }

  float* outp = kvp + ((size_t)(chunk * 64 + bh) << 14);
  #pragma unroll
  for (int j = 0; j < 8; ++j) {
    int e = (te << 3) + j;
    float r0[8];
    #pragma unroll
    for (int i = 0; i < 8; ++i) r0[i] = acc[i][j];
    *(float4*)&outp[(size_t)e * HDIM + (td << 3)]     = *(float4*)&r0[0];
    *(float4*)&outp[(size_t)e * HDIM + (td << 3) + 4] = *(float4*)&r0[4];
  }
  if (te == 0) {
    float* kso = ksp + ((size_t)(chunk * 64 + bh) << 7) + (td << 3);
    #pragma unroll
    for (int i = 0; i < 8; ++i) kso[i] = ks[i];
  }
}

__global__ __launch_bounds__(256) void kv_reduce(
    const float* __restrict__ kvp, float* __restrict__ kvT)
{
  int i = blockIdx.x * 256 + threadIdx.x;
  float s = 0.f;
  #pragma unroll
  for (int c = 0; c < 16; ++c) s += kvp[(size_t)c * (64 * 16384) + i];
  kvT[i] = s;
}

// attn[s,e] = (qp[s,:] . kvT[e,:]) / (z[s]+eps); qp = q cols of qkv, out -> v cols.
__global__ __launch_bounds__(256) void attn_ker(
    const unsigned short* __restrict__ qp, const float* __restrict__ kvT,
    const float* __restrict__ ksp, unsigned short* __restrict__ attn)
{
  const int bh = blockIdx.x >> 5, stile = blockIdx.x & 31;
  const int b = bh >> 4, h = bh & 15;
  const int tid = threadIdx.x;
  const int lane = tid & 63, w = tid >> 6;
  const int l15 = lane & 15, l4 = lane >> 4;

  __shared__ unsigned short Qs[128][136];
  __shared__ unsigned short Ks[128][136];
  __shared__ float ksl[128];
  __shared__ float zs[128];

  const size_t qbase = ((size_t)b * NS + (size_t)stile * 128) * QSTR + (size_t)h * HDIM;

  #pragma unroll
  for (int i = 0; i < 8; ++i) {
    int idx = tid + (i << 8);
    int row = idx >> 4, q = idx & 15;
    u16x8 v8 = *(const u16x8*)(qp + qbase + (size_t)row * QSTR + (q << 3));
    *(u16x8*)&Qs[row][q << 3] = v8;
  }
  const float* kvb = kvT + ((size_t)bh << 14);
  #pragma unroll
  for (int i = 0; i < 16; ++i) {
    int idx = tid + (i << 8);
    int row = idx >> 5, q = idx & 31;
    float4 v4 = *(const float4*)(kvb + (size_t)row * HDIM + (q << 2));
    ushort4 w4; w4.x = f2b(v4.x); w4.y = f2b(v4.y); w4.z = f2b(v4.z); w4.w = f2b(v4.w);
    *(ushort4*)&Ks[row][q << 2] = w4;
  }
  if (tid < 128) {
    float s = 0.f;
    #pragma unroll
    for (int c = 0; c < 16; ++c) s += ksp[((size_t)(c * 64 + bh) << 7) + tid];
    ksl[tid] = s;
  }
  __syncthreads();
  if (tid < 128) {
    float z = 0.f;
    #pragma unroll
    for (int dq = 0; dq < 16; ++dq) {
      u16x8 qv = *(const u16x8*)&Qs[tid][dq << 3];
      #pragma unroll
      for (int j = 0; j < 8; ++j) z += b2f(qv[j]) * ksl[(dq << 3) + j];
    }
    zs[tid] = 1.f / (z + EPSV);
  }
  __syncthreads();

  f32x4 acc[2][8] = {};
  #pragma unroll
  for (int kk = 0; kk < 4; ++kk) {
    s16x8 a[2], bb[8];
    #pragma unroll
    for (int mf = 0; mf < 2; ++mf)
      a[mf] = *(const s16x8*)&Qs[(w << 5) + (mf << 4) + l15][(kk << 5) + (l4 << 3)];
    #pragma unroll
    for (int nf = 0; nf < 8; ++nf)
      bb[nf] = *(const s16x8*)&Ks[(nf << 4) + l15][(kk << 5) + (l4 << 3)];
    #pragma unroll
    for (int mf = 0; mf < 2; ++mf)
      #pragma unroll
      for (int nf = 0; nf < 8; ++nf)
        acc[mf][nf] = __builtin_amdgcn_mfma_f32_16x16x32_bf16(a[mf], bb[nf], acc[mf][nf], 0, 0, 0);
  }

  #pragma unroll
  for (int mf = 0; mf < 2; ++mf) {
    #pragma unroll
    for (int r = 0; r < 4; ++r) {
      const int rl = (w << 5) + (mf << 4) + (l4 << 2) + r;
      const float zi = zs[rl];
      #pragma unroll
      for (int nf = 0; nf < 8; ++nf) {
        const int e = (nf << 4) + l15;
        attn[qbase + (size_t)rl * QSTR + e] = f2b(acc[mf][nf][r] * zi);
      }
    }
  }
}

extern "C" void kernel_launch(void* const* d_in, const int* in_sizes, int n_in,
                              void* d_out, int out_size, void* d_ws, size_t ws_size,
                              hipStream_t stream) {
  const float* hs = (const float*)d_in[0];
  const float* qw = (const float*)d_in[1];
  const float* qb = (const float*)d_in[2];
  const float* kw = (const float*)d_in[3];
  const float* kb = (const float*)d_in[4];
  const float* vw = (const float*)d_in[5];
  const float* vb = (const float*)d_in[6];
  const float* ow = (const float*)d_in[7];
  const float* ob = (const float*)d_in[8];

  char* w = (char*)d_ws;
  unsigned short* hsb = (unsigned short*)(w);                  // 64 MiB (dead after QKV gemm)
  unsigned short* qwb = (unsigned short*)(w + 67108864);       // 8 MiB each (q/k/v dead after QKV)
  unsigned short* kwb = (unsigned short*)(w + 75497472);
  unsigned short* vwb = (unsigned short*)(w + 83886080);
  unsigned short* owb = (unsigned short*)(w + 92274688);
  unsigned short* qkv = (unsigned short*)(w + 100663296);      // 192 MiB, row stride 6144
  // aliases over dead regions after QKV:
  float* kvp = (float*)(w);                                    // 64 MiB (16 chunks) over hsb
  float* ksp = (float*)(w + 67108864);                         // 512 KiB over qwb
  float* kvT = (float*)(w + 67108864 + 524288);                // 4 MiB over qwb

  convert_all<<<dim3(24576), dim3(256), 0, stream>>>(hs, qw, kw, vw, ow, hsb, qwb, kwb, vwb, owb);
  // QKV fused: M=16384, N=6144 (q|k|v columns), elu+1 on q,k. 64x48 = 3072 blocks.
  gemm256<1, 1><<<dim3(3072), dim3(256), 0, stream>>>(
      hsb, qwb, kwb, vwb, qb, kb, vb, qkv, 48, HIDC, QSTR);
  kv_partial<<<dim3(1024), dim3(256), 0, stream>>>(qkv + 2048, qkv + 4096, kvp, ksp);
  kv_reduce<<<dim3(4096), dim3(256), 0, stream>>>(kvp, kvT);
  attn_ker<<<dim3(2048), dim3(256), 0, stream>>>(qkv, kvT, ksp, qkv + 4096);
  // final: out = attn @ o_w^T + o_b, A = v-columns of qkv (astr=QSTR), fp32 out. 64x16 = 1024 blocks.
  gemm256<0, 0><<<dim3(1024), dim3(256), 0, stream>>>(
      qkv + 4096, owb, owb, owb, ob, ob, ob, d_out, 16, QSTR, HIDC);
}

// Round 11
// 784.463 us; speedup vs baseline: 1.0268x; 1.0268x over previous
//
#include <hip/hip_runtime.h>
#include <hip/hip_bf16.h>

#define HIDC 2048
#define NHEADS 16
#define HDIM 128
#define NB 4
#define NS 4096
#define NROWS (NB*NS)
#define QSTR 6144
#define EPSV 1e-6f

typedef __attribute__((ext_vector_type(8))) short s16x8;
typedef __attribute__((ext_vector_type(4))) float f32x4;
typedef __attribute__((ext_vector_type(8))) unsigned short u16x8;

static __device__ __forceinline__ unsigned short f2b(float f) {
  unsigned int u = __float_as_uint(f);
  u += 0x7fffu + ((u >> 16) & 1u);
  return (unsigned short)(u >> 16);
}
static __device__ __forceinline__ float b2f(unsigned short h) {
  return __uint_as_float(((unsigned int)h) << 16);
}

static __device__ __forceinline__ void gload_lds16(const unsigned short* g, unsigned short* l) {
  __builtin_amdgcn_global_load_lds(
      (const __attribute__((address_space(1))) void*)g,
      (__attribute__((address_space(3))) void*)l, 16, 0, 0);
}

// fp32 -> bf16 conversion for hs (16384 blocks) + 4 weights (2048 blocks each)
__global__ __launch_bounds__(256) void convert_all(
    const float* __restrict__ hs, const float* __restrict__ qw,
    const float* __restrict__ kw, const float* __restrict__ vw,
    const float* __restrict__ ow,
    unsigned short* __restrict__ hsb, unsigned short* __restrict__ qwb,
    unsigned short* __restrict__ kwb, unsigned short* __restrict__ vwb,
    unsigned short* __restrict__ owb)
{
  int bid = blockIdx.x;
  const float* src; unsigned short* dst; size_t base;
  if (bid < 16384) { src = hs; dst = hsb; base = (size_t)bid << 11; }
  else {
    int t = bid - 16384; int wsel = t >> 11; int wb = t & 2047;
    src = wsel == 0 ? qw : wsel == 1 ? kw : wsel == 2 ? vw : ow;
    dst = wsel == 0 ? qwb : wsel == 1 ? kwb : wsel == 2 ? vwb : owb;
    base = (size_t)wb << 11;
  }
  size_t i = base + ((size_t)threadIdx.x << 3);
  float4 a = *(const float4*)(src + i);
  float4 b = *(const float4*)(src + i + 4);
  u16x8 o;
  o[0] = f2b(a.x); o[1] = f2b(a.y); o[2] = f2b(a.z); o[3] = f2b(a.w);
  o[4] = f2b(b.x); o[5] = f2b(b.y); o[6] = f2b(b.z); o[7] = f2b(b.w);
  *(u16x8*)(dst + i) = o;
}

// m201-template port: 256x256 tile, 8 waves (2Mx4N), BK=64, 2 LDS buffers
// (64 KB each: A[kk0|kk1 panels 256x32] + B[same]), stage 1 K-tile ahead as
// 4 half-tiles (one per phase), 4 phases x 16 MFMA, reads-before-bar +
// lgkmcnt(0)-after-bar, counted vmcnt(4) gates at end of P1 and P3.
// Gate accounting (2 loads/half-tile/wave): entering tile t, t.H2/H3 are the
// 4 outstanding; gate@P1 drains them before P2 reads kk1; gate@P3 drains
// t+1.H0/H1 before t+1.P0. Ring-2 => stage writes touch the buffer fully
// consumed last tile (reads lgkm-drained pre-MFMA pre-barrier) - no WAR.
// XOR-swizzle: slot' = l4 ^ ((row>>1)&3) on 4x16B slots (2-way = free).
template<int QKV, int OUT_BF16>
__global__ __launch_bounds__(512, 1) void gemm256(
    const unsigned short* __restrict__ A,
    const unsigned short* __restrict__ B0,
    const unsigned short* __restrict__ B1,
    const unsigned short* __restrict__ B2,
    const float* __restrict__ bias0,
    const float* __restrict__ bias1,
    const float* __restrict__ bias2,
    void* __restrict__ Cp,
    int ntile, int astr, int ostr)
{
  __shared__ unsigned short lds[65536];   // 128 KiB: 2 buf x [A:16384][B:16384]
  const int tid = threadIdx.x;
  const int lane = tid & 63, wid = tid >> 6;
  const int wr = wid >> 2, wc = wid & 3;
  const int l15 = lane & 15, l4 = lane >> 4;

  // bijective XCD swizzle (grid % 8 == 0) + L2 chunking: 4 bm x all bn
  const int cpx = (int)gridDim.x >> 3;
  const int bidx = (int)blockIdx.x;
  const int wg = (bidx & 7) * cpx + (bidx >> 3);
  const int csz = ntile << 2;
  const int chunk = wg / csz;
  const int tt = wg % csz;
  const int bm = ((chunk << 2) + (tt & 3)) << 8;
  const int bn = (tt >> 2) << 8;

  const unsigned short* Bp = B0;
  const float* bias = bias0;
  bool act = false;
  int bnw = bn;
  if (QKV) {
    int seg = bn >> 11;
    Bp = seg == 0 ? B0 : (seg == 1 ? B1 : B2);
    bias = seg == 0 ? bias0 : (seg == 1 ? bias1 : bias2);
    act = seg < 2;
    bnw = bn & 2047;
  }

  // staging: half-tile = 256 rows x 32 cols (16 KB) = 2 gload_lds/thread.
  // thread -> row r0 = tid>>2 (+128 for 2nd load), slot s0 = tid&3;
  // source col inverse-swizzled so linear LDS write + swizzled read agree.
  const int r0 = tid >> 2;
  const int s0 = tid & 3;
  const int scol = ((s0 ^ ((r0 >> 1) & 3)) << 3);
  const unsigned short* ApA  = A  + (size_t)(bm  + r0) * astr + scol;
  const unsigned short* ApA2 = ApA + (size_t)128 * astr;
  const unsigned short* BpB  = Bp + (size_t)(bnw + r0) * HIDC + scol;
  const unsigned short* BpB2 = BpB + (size_t)128 * HIDC;

  // fragment read offsets: row*32 + ((l4 ^ ((row>>1)&3))<<3); kk panel +8192
  const int xa = ((l4 ^ ((l15 >> 1) & 3)) << 3);
  const int abase = ((wr << 7) + l15) * 32 + xa;
  const int bbase = 16384 + ((wc << 6) + l15) * 32 + xa;

  f32x4 acc[8][4] = {};
  s16x8 af[8], bf2[4];

#define LD(off_) (*(const s16x8*)&lds[off_])
#define ST_A(kk_, kt_) { \
    gload_lds16(ApA  + (kt_) + ((kk_) << 5), &lds[wb + ((kk_) << 13) + (tid << 3)]); \
    gload_lds16(ApA2 + (kt_) + ((kk_) << 5), &lds[wb + ((kk_) << 13) + 4096 + (tid << 3)]); }
#define ST_B(kk_, kt_) { \
    gload_lds16(BpB  + (kt_) + ((kk_) << 5), &lds[wb + 16384 + ((kk_) << 13) + (tid << 3)]); \
    gload_lds16(BpB2 + (kt_) + ((kk_) << 5), &lds[wb + 16384 + ((kk_) << 13) + 4096 + (tid << 3)]); }
#define MM16(i0_, i1_, i2_, i3_) { \
    acc[i0_][0] = __builtin_amdgcn_mfma_f32_16x16x32_bf16(af[i0_], bf2[0], acc[i0_][0], 0, 0, 0); \
    acc[i0_][1] = __builtin_amdgcn_mfma_f32_16x16x32_bf16(af[i0_], bf2[1], acc[i0_][1], 0, 0, 0); \
    acc[i0_][2] = __builtin_amdgcn_mfma_f32_16x16x32_bf16(af[i0_], bf2[2], acc[i0_][2], 0, 0, 0); \
    acc[i0_][3] = __builtin_amdgcn_mfma_f32_16x16x32_bf16(af[i0_], bf2[3], acc[i0_][3], 0, 0, 0); \
    acc[i1_][0] = __builtin_amdgcn_mfma_f32_16x16x32_bf16(af[i1_], bf2[0], acc[i1_][0], 0, 0, 0); \
    acc[i1_][1] = __builtin_amdgcn_mfma_f32_16x16x32_bf16(af[i1_], bf2[1], acc[i1_][1], 0, 0, 0); \
    acc[i1_][2] = __builtin_amdgcn_mfma_f32_16x16x32_bf16(af[i1_], bf2[2], acc[i1_][2], 0, 0, 0); \
    acc[i1_][3] = __builtin_amdgcn_mfma_f32_16x16x32_bf16(af[i1_], bf2[3], acc[i1_][3], 0, 0, 0); \
    acc[i2_][0] = __builtin_amdgcn_mfma_f32_16x16x32_bf16(af[i2_], bf2[0], acc[i2_][0], 0, 0, 0); \
    acc[i2_][1] = __builtin_amdgcn_mfma_f32_16x16x32_bf16(af[i2_], bf2[1], acc[i2_][1], 0, 0, 0); \
    acc[i2_][2] = __builtin_amdgcn_mfma_f32_16x16x32_bf16(af[i2_], bf2[2], acc[i2_][2], 0, 0, 0); \
    acc[i2_][3] = __builtin_amdgcn_mfma_f32_16x16x32_bf16(af[i2_], bf2[3], acc[i2_][3], 0, 0, 0); \
    acc[i3_][0] = __builtin_amdgcn_mfma_f32_16x16x32_bf16(af[i3_], bf2[0], acc[i3_][0], 0, 0, 0); \
    acc[i3_][1] = __builtin_amdgcn_mfma_f32_16x16x32_bf16(af[i3_], bf2[1], acc[i3_][1], 0, 0, 0); \
    acc[i3_][2] = __builtin_amdgcn_mfma_f32_16x16x32_bf16(af[i3_], bf2[2], acc[i3_][2], 0, 0, 0); \
    acc[i3_][3] = __builtin_amdgcn_mfma_f32_16x16x32_bf16(af[i3_], bf2[3], acc[i3_][3], 0, 0, 0); }
#define SB   __builtin_amdgcn_sched_barrier(0);
#define BAR  __builtin_amdgcn_s_barrier();
#define LGKM0 asm volatile("s_waitcnt lgkmcnt(0)" ::: "memory");
#define PRON __builtin_amdgcn_s_setprio(1);
#define PROFF __builtin_amdgcn_s_setprio(0);
#define GATE(G_) { if ((G_) == 4) { asm volatile("s_waitcnt vmcnt(4)" ::: "memory"); } \
                   else if ((G_) == 0) { asm volatile("s_waitcnt vmcnt(0)" ::: "memory"); } }

#define DO_TILE(t_, STG, G1, G3) { \
    const int rb = ((t_) & 1) << 15; \
    const int wb = rb ^ 32768; (void)wb; \
    const int kts = ((t_) + 1) << 6; (void)kts; \
    /* P0: b(kk0) + a0-3(kk0); stage t+1.A-kk0 */ \
    bf2[0] = LD(rb + bbase);        bf2[1] = LD(rb + bbase + 512); \
    bf2[2] = LD(rb + bbase + 1024); bf2[3] = LD(rb + bbase + 1536); \
    af[0] = LD(rb + abase);         af[1] = LD(rb + abase + 512); \
    af[2] = LD(rb + abase + 1024);  af[3] = LD(rb + abase + 1536); \
    if (STG) ST_A(0, kts); \
    SB BAR LGKM0 PRON MM16(0, 1, 2, 3) PROFF BAR \
    /* P1: a4-7(kk0); stage t+1.B-kk0; gate */ \
    af[4] = LD(rb + abase + 2048);  af[5] = LD(rb + abase + 2560); \
    af[6] = LD(rb + abase + 3072);  af[7] = LD(rb + abase + 3584); \
    if (STG) ST_B(0, kts); \
    SB BAR LGKM0 PRON MM16(4, 5, 6, 7) PROFF GATE(G1) BAR \
    /* P2: b(kk1) + a0-3(kk1); stage t+1.A-kk1 */ \
    bf2[0] = LD(rb + 8192 + bbase);        bf2[1] = LD(rb + 8192 + bbase + 512); \
    bf2[2] = LD(rb + 8192 + bbase + 1024); bf2[3] = LD(rb + 8192 + bbase + 1536); \
    af[0] = LD(rb + 8192 + abase);         af[1] = LD(rb + 8192 + abase + 512); \
    af[2] = LD(rb + 8192 + abase + 1024);  af[3] = LD(rb + 8192 + abase + 1536); \
    if (STG) ST_A(1, kts); \
    SB BAR LGKM0 PRON MM16(0, 1, 2, 3) PROFF BAR \
    /* P3: a4-7(kk1); stage t+1.B-kk1; gate */ \
    af[4] = LD(rb + 8192 + abase + 2048);  af[5] = LD(rb + 8192 + abase + 2560); \
    af[6] = LD(rb + 8192 + abase + 3072);  af[7] = LD(rb + 8192 + abase + 3584); \
    if (STG) ST_B(1, kts); \
    SB BAR LGKM0 PRON MM16(4, 5, 6, 7) PROFF GATE(G3) BAR \
  }

  // prologue: stage tile 0's four half-tiles; vmcnt(4) leaves H2,H3 (steady state)
  {
    const int wb = 0;
    ST_A(0, 0); ST_B(0, 0); ST_A(1, 0); ST_B(1, 0);
  }
  asm volatile("s_waitcnt vmcnt(4)" ::: "memory");
  __builtin_amdgcn_s_barrier();

  for (int t = 0; t < 31; ++t) DO_TILE(t, 1, 4, 4)
  DO_TILE(31, 0, 0, -1)

#undef DO_TILE
#undef GATE
#undef PROFF
#undef PRON
#undef LGKM0
#undef BAR
#undef SB
#undef MM16
#undef ST_B
#undef ST_A
#undef LD

  #pragma unroll
  for (int nf = 0; nf < 4; ++nf) {
    const int colw = (wc << 6) + (nf << 4) + l15;
    const float bv = bias[bnw + colw];
    #pragma unroll
    for (int mf = 0; mf < 8; ++mf) {
      #pragma unroll
      for (int r = 0; r < 4; ++r) {
        const int row = bm + (wr << 7) + (mf << 4) + (l4 << 2) + r;
        float v = acc[mf][nf][r] + bv;
        if (QKV) { if (act) v = (v > 0.f) ? (v + 1.f) : __expf(v); }
        const size_t off = (size_t)row * ostr + bn + colw;
        if (OUT_BF16) ((unsigned short*)Cp)[off] = f2b(v);
        else          ((float*)Cp)[off] = v;
      }
    }
  }
}

// kv partials over 16 S-chunks (deterministic, no atomics). 1024 blocks -> 4/CU.
__global__ __launch_bounds__(256) void kv_partial(
    const unsigned short* __restrict__ kp, const unsigned short* __restrict__ vv,
    float* __restrict__ kvp, float* __restrict__ ksp)
{
  const int bh = blockIdx.x >> 4;
  const int chunk = blockIdx.x & 15;
  const int b = bh >> 4, h = bh & 15;
  const int tid = threadIdx.x;
  const int td = tid >> 4, te = tid & 15;

  __shared__ float kpl[32][128];
  __shared__ float vl[32][132];

  float acc[8][8] = {};
  float ks[8] = {};

  const size_t rowbase = (size_t)b * NS * QSTR + (size_t)h * HDIM;
  const int s0 = chunk * 256;

  for (int st = 0; st < 256; st += 32) {
    __syncthreads();
    #pragma unroll
    for (int i = 0; i < 2; ++i) {
      int idx = tid + (i << 8);
      int row = idx >> 4, q = idx & 15;
      size_t g = rowbase + (size_t)(s0 + st + row) * QSTR + (q << 3);
      u16x8 k8 = *(const u16x8*)(kp + g);
      u16x8 v8 = *(const u16x8*)(vv + g);
      float tk[8], tv[8];
      #pragma unroll
      for (int j = 0; j < 8; ++j) { tk[j] = b2f(k8[j]); tv[j] = b2f(v8[j]); }
      *(float4*)&kpl[row][(q << 3)]     = make_float4(tk[0], tk[1], tk[2], tk[3]);
      *(float4*)&kpl[row][(q << 3) + 4] = make_float4(tk[4], tk[5], tk[6], tk[7]);
      *(float4*)&vl[row][(q << 3)]      = make_float4(tv[0], tv[1], tv[2], tv[3]);
      *(float4*)&vl[row][(q << 3) + 4]  = make_float4(tv[4], tv[5], tv[6], tv[7]);
    }
    __syncthreads();
    #pragma unroll 4
    for (int s = 0; s < 32; ++s) {
      float kd[8], ve[8];
      *(float4*)&kd[0] = *(const float4*)&kpl[s][td << 3];
      *(float4*)&kd[4] = *(const float4*)&kpl[s][(td << 3) + 4];
      *(float4*)&ve[0] = *(const float4*)&vl[s][te << 3];
      *(float4*)&ve[4] = *(const float4*)&vl[s][(te << 3) + 4];
      if (te == 0) {
        #pragma unroll
        for (int i = 0; i < 8; ++i) ks[i] += kd[i];
      }
      #pragma unroll
      for (int i = 0; i < 8; ++i)
        #pragma unroll
        for (int j = 0; j < 8; ++j)
          acc[i][j] += kd[i] * ve[j];
    }
  }

  float* outp = kvp + ((size_t)(chunk * 64 + bh) << 14);
  #pragma unroll
  for (int j = 0; j < 8; ++j) {
    int e = (te << 3) + j;
    float r0[8];
    #pragma unroll
    for (int i = 0; i < 8; ++i) r0[i] = acc[i][j];
    *(float4*)&outp[(size_t)e * HDIM + (td << 3)]     = *(float4*)&r0[0];
    *(float4*)&outp[(size_t)e * HDIM + (td << 3) + 4] = *(float4*)&r0[4];
  }
  if (te == 0) {
    float* kso = ksp + ((size_t)(chunk * 64 + bh) << 7) + (td << 3);
    #pragma unroll
    for (int i = 0; i < 8; ++i) kso[i] = ks[i];
  }
}

__global__ __launch_bounds__(256) void kv_reduce(
    const float* __restrict__ kvp, float* __restrict__ kvT)
{
  int i = blockIdx.x * 256 + threadIdx.x;
  float s = 0.f;
  #pragma unroll
  for (int c = 0; c < 16; ++c) s += kvp[(size_t)c * (64 * 16384) + i];
  kvT[i] = s;
}

// attn[s,e] = (qp[s,:] . kvT[e,:]) / (z[s]+eps); qp = q cols of qkv, out -> v cols.
__global__ __launch_bounds__(256) void attn_ker(
    const unsigned short* __restrict__ qp, const float* __restrict__ kvT,
    const float* __restrict__ ksp, unsigned short* __restrict__ attn)
{
  const int bh = blockIdx.x >> 5, stile = blockIdx.x & 31;
  const int b = bh >> 4, h = bh & 15;
  const int tid = threadIdx.x;
  const int lane = tid & 63, w = tid >> 6;
  const int l15 = lane & 15, l4 = lane >> 4;

  __shared__ unsigned short Qs[128][136];
  __shared__ unsigned short Ks[128][136];
  __shared__ float ksl[128];
  __shared__ float zs[128];

  const size_t qbase = ((size_t)b * NS + (size_t)stile * 128) * QSTR + (size_t)h * HDIM;

  #pragma unroll
  for (int i = 0; i < 8; ++i) {
    int idx = tid + (i << 8);
    int row = idx >> 4, q = idx & 15;
    u16x8 v8 = *(const u16x8*)(qp + qbase + (size_t)row * QSTR + (q << 3));
    *(u16x8*)&Qs[row][q << 3] = v8;
  }
  const float* kvb = kvT + ((size_t)bh << 14);
  #pragma unroll
  for (int i = 0; i < 16; ++i) {
    int idx = tid + (i << 8);
    int row = idx >> 5, q = idx & 31;
    float4 v4 = *(const float4*)(kvb + (size_t)row * HDIM + (q << 2));
    ushort4 w4; w4.x = f2b(v4.x); w4.y = f2b(v4.y); w4.z = f2b(v4.z); w4.w = f2b(v4.w);
    *(ushort4*)&Ks[row][q << 2] = w4;
  }
  if (tid < 128) {
    float s = 0.f;
    #pragma unroll
    for (int c = 0; c < 16; ++c) s += ksp[((size_t)(c * 64 + bh) << 7) + tid];
    ksl[tid] = s;
  }
  __syncthreads();
  if (tid < 128) {
    float z = 0.f;
    #pragma unroll
    for (int dq = 0; dq < 16; ++dq) {
      u16x8 qv = *(const u16x8*)&Qs[tid][dq << 3];
      #pragma unroll
      for (int j = 0; j < 8; ++j) z += b2f(qv[j]) * ksl[(dq << 3) + j];
    }
    zs[tid] = 1.f / (z + EPSV);
  }
  __syncthreads();

  f32x4 acc[2][8] = {};
  #pragma unroll
  for (int kk = 0; kk < 4; ++kk) {
    s16x8 a[2], bb[8];
    #pragma unroll
    for (int mf = 0; mf < 2; ++mf)
      a[mf] = *(const s16x8*)&Qs[(w << 5) + (mf << 4) + l15][(kk << 5) + (l4 << 3)];
    #pragma unroll
    for (int nf = 0; nf < 8; ++nf)
      bb[nf] = *(const s16x8*)&Ks[(nf << 4) + l15][(kk << 5) + (l4 << 3)];
    #pragma unroll
    for (int mf = 0; mf < 2; ++mf)
      #pragma unroll
      for (int nf = 0; nf < 8; ++nf)
        acc[mf][nf] = __builtin_amdgcn_mfma_f32_16x16x32_bf16(a[mf], bb[nf], acc[mf][nf], 0, 0, 0);
  }

  #pragma unroll
  for (int mf = 0; mf < 2; ++mf) {
    #pragma unroll
    for (int r = 0; r < 4; ++r) {
      const int rl = (w << 5) + (mf << 4) + (l4 << 2) + r;
      const float zi = zs[rl];
      #pragma unroll
      for (int nf = 0; nf < 8; ++nf) {
        const int e = (nf << 4) + l15;
        attn[qbase + (size_t)rl * QSTR + e] = f2b(acc[mf][nf][r] * zi);
      }
    }
  }
}

extern "C" void kernel_launch(void* const* d_in, const int* in_sizes, int n_in,
                              void* d_out, int out_size, void* d_ws, size_t ws_size,
                              hipStream_t stream) {
  const float* hs = (const float*)d_in[0];
  const float* qw = (const float*)d_in[1];
  const float* qb = (const float*)d_in[2];
  const float* kw = (const float*)d_in[3];
  const float* kb = (const float*)d_in[4];
  const float* vw = (const float*)d_in[5];
  const float* vb = (const float*)d_in[6];
  const float* ow = (const float*)d_in[7];
  const float* ob = (const float*)d_in[8];

  char* w = (char*)d_ws;
  unsigned short* hsb = (unsigned short*)(w);                  // 64 MiB (dead after QKV gemm)
  unsigned short* qwb = (unsigned short*)(w + 67108864);       // 8 MiB each (q/k/v dead after QKV)
  unsigned short* kwb = (unsigned short*)(w + 75497472);
  unsigned short* vwb = (unsigned short*)(w + 83886080);
  unsigned short* owb = (unsigned short*)(w + 92274688);
  unsigned short* qkv = (unsigned short*)(w + 100663296);      // 192 MiB, row stride 6144
  // aliases over dead regions after QKV:
  float* kvp = (float*)(w);                                    // 64 MiB (16 chunks) over hsb
  float* ksp = (float*)(w + 67108864);                         // 512 KiB over qwb
  float* kvT = (float*)(w + 67108864 + 524288);                // 4 MiB over qwb

  convert_all<<<dim3(24576), dim3(256), 0, stream>>>(hs, qw, kw, vw, ow, hsb, qwb, kwb, vwb, owb);
  // QKV fused: M=16384, N=6144 (q|k|v columns), elu+1 on q,k. 64x24 = 1536 blocks.
  gemm256<1, 1><<<dim3(1536), dim3(512), 0, stream>>>(
      hsb, qwb, kwb, vwb, qb, kb, vb, qkv, 24, HIDC, QSTR);
  kv_partial<<<dim3(1024), dim3(256), 0, stream>>>(qkv + 2048, qkv + 4096, kvp, ksp);
  kv_reduce<<<dim3(4096), dim3(256), 0, stream>>>(kvp, kvT);
  attn_ker<<<dim3(2048), dim3(256), 0, stream>>>(qkv, kvT, ksp, qkv + 4096);
  // final: out = attn @ o_w^T + o_b, A = v-columns of qkv (astr=QSTR), fp32 out. 64x8 = 512 blocks.
  gemm256<0, 0><<<dim3(512), dim3(512), 0, stream>>>(
      qkv + 4096, owb, owb, owb, ob, ob, ob, d_out, 8, QSTR, HIDC);
}

// Round 12
// 771.415 us; speedup vs baseline: 1.0442x; 1.0169x over previous
//
#include <hip/hip_runtime.h>
#include <hip/hip_bf16.h>

#define HIDC 2048
#define NHEADS 16
#define HDIM 128
#define NB 4
#define NS 4096
#define NROWS (NB*NS)
#define QSTR 6144
#define EPSV 1e-6f

typedef __attribute__((ext_vector_type(8))) short s16x8;
typedef __attribute__((ext_vector_type(4))) float f32x4;
typedef __attribute__((ext_vector_type(16))) float f32x16;
typedef __attribute__((ext_vector_type(8))) unsigned short u16x8;

static __device__ __forceinline__ unsigned short f2b(float f) {
  unsigned int u = __float_as_uint(f);
  u += 0x7fffu + ((u >> 16) & 1u);
  return (unsigned short)(u >> 16);
}
static __device__ __forceinline__ float b2f(unsigned short h) {
  return __uint_as_float(((unsigned int)h) << 16);
}

static __device__ __forceinline__ void gload_lds16(const unsigned short* g, unsigned short* l) {
  __builtin_amdgcn_global_load_lds(
      (const __attribute__((address_space(1))) void*)g,
      (__attribute__((address_space(3))) void*)l, 16, 0, 0);
}

// fp32 -> bf16 conversion for hs (16384 blocks) + 4 weights (2048 blocks each)
__global__ __launch_bounds__(256) void convert_all(
    const float* __restrict__ hs, const float* __restrict__ qw,
    const float* __restrict__ kw, const float* __restrict__ vw,
    const float* __restrict__ ow,
    unsigned short* __restrict__ hsb, unsigned short* __restrict__ qwb,
    unsigned short* __restrict__ kwb, unsigned short* __restrict__ vwb,
    unsigned short* __restrict__ owb)
{
  int bid = blockIdx.x;
  const float* src; unsigned short* dst; size_t base;
  if (bid < 16384) { src = hs; dst = hsb; base = (size_t)bid << 11; }
  else {
    int t = bid - 16384; int wsel = t >> 11; int wb = t & 2047;
    src = wsel == 0 ? qw : wsel == 1 ? kw : wsel == 2 ? vw : ow;
    dst = wsel == 0 ? qwb : wsel == 1 ? kwb : wsel == 2 ? vwb : owb;
    base = (size_t)wb << 11;
  }
  size_t i = base + ((size_t)threadIdx.x << 3);
  float4 a = *(const float4*)(src + i);
  float4 b = *(const float4*)(src + i + 4);
  u16x8 o;
  o[0] = f2b(a.x); o[1] = f2b(a.y); o[2] = f2b(a.z); o[3] = f2b(a.w);
  o[4] = f2b(b.x); o[5] = f2b(b.y); o[6] = f2b(b.z); o[7] = f2b(b.w);
  *(u16x8*)(dst + i) = o;
}

// 256x256-tile bf16 GEMM on mfma_f32_32x32x16_bf16 (2382-2495 TF ceiling vs
// 2075 for 16x16 -> MFMA floor/tile 2484->2066 cyc, half the instructions).
// 8 waves (2Mx4N, wave-tile 128x64 = 4x2 32x32 frags), BK=64, ring-2 LDS
// buffers (64 KB each: A[kk0|kk1]+B[kk0|kk1] panels of 256rows x 32cols),
// 2 phases/tile {gate vmcnt(4) | bar | 12 ds_read | stage half(t+1) | SB |
// 16 MFMA}, compiler-counted lgkm waits (no full drains).
// Swizzle (re-derived for 32x32 frag): slot' = s ^ ((row>>3)&3) -> 2 lanes/
// granule (free); staging pre-swizzles global col with same involution.
// A-frag: lane=(row l&31, k-half l>>5); C/D: col=l&31,
// row=(reg&3)+8*(reg>>2)+4*(l>>5)  [m74/m101-verified mapping].
template<int QKV, int OUT_BF16>
__global__ __launch_bounds__(512, 1) void gemm256(
    const unsigned short* __restrict__ A,
    const unsigned short* __restrict__ B0,
    const unsigned short* __restrict__ B1,
    const unsigned short* __restrict__ B2,
    const float* __restrict__ bias0,
    const float* __restrict__ bias1,
    const float* __restrict__ bias2,
    void* __restrict__ Cp,
    int ntile, int astr, int ostr)
{
  __shared__ unsigned short lds[65536];   // 2 buf x [A:16384][B:16384]
  const int tid = threadIdx.x;
  const int lane = tid & 63, wid = tid >> 6;
  const int wr = wid >> 2, wc = wid & 3;
  const int l31 = lane & 31, l5 = lane >> 5;

  // bijective XCD swizzle (grid % 8 == 0) + L2 chunking: 4 bm x all bn
  const int cpx = (int)gridDim.x >> 3;
  const int bidx = (int)blockIdx.x;
  const int wg = (bidx & 7) * cpx + (bidx >> 3);
  const int csz = ntile << 2;
  const int chunk = wg / csz;
  const int tt = wg % csz;
  const int bm = ((chunk << 2) + (tt & 3)) << 8;
  const int bn = (tt >> 2) << 8;

  const unsigned short* Bp = B0;
  const float* bias = bias0;
  bool act = false;
  int bnw = bn;
  if (QKV) {
    int seg = bn >> 11;
    Bp = seg == 0 ? B0 : (seg == 1 ? B1 : B2);
    bias = seg == 0 ? bias0 : (seg == 1 ? bias1 : bias2);
    act = seg < 2;
    bnw = bn & 2047;
  }

  // staging: half-tile = one 256x32 panel of A + one of B (16 KB each).
  // thread -> row r0 = tid>>2 (+128 for 2nd load), 16B slot s0 = tid&3;
  // source col inverse-swizzled: scol = (s0 ^ ((r0>>3)&3))*8  (same for
  // r0+128 since (+128)>>3 = +16 == 0 mod 4).
  const int r0 = tid >> 2;
  const int s0 = tid & 3;
  const int scol = ((s0 ^ ((r0 >> 3) & 3)) << 3);
  const unsigned short* ApA  = A  + (size_t)(bm  + r0) * astr + scol;
  const unsigned short* ApA2 = ApA + (size_t)128 * astr;
  const unsigned short* BpB  = Bp + (size_t)(bnw + r0) * HIDC + scol;
  const unsigned short* BpB2 = BpB + (size_t)128 * HIDC;

  // fragment read addressing: row r = base + l31, slot s_nat = 2j + l5,
  // swizzled s' = s_nat ^ ((l31>>3)&3) (frag base rows are 32-aligned).
  const int xr = (l31 >> 3) & 3;
  const int sj0 = ((l5 ^ xr) << 3);
  const int sj1 = (((2 + l5) ^ xr) << 3);
  const int abase = ((wr << 7) + l31) * 32;           // + mf*1024 + kk*8192 + sj
  const int bbase = 16384 + ((wc << 6) + l31) * 32;   // + nf*1024 + kk*8192 + sj

  f32x16 acc[4][2] = {};
  s16x8 a[4][2], b[2][2];

#define LD(off_) (*(const s16x8*)&lds[off_])
#define ST_A(kk_, kt_) { \
    gload_lds16(ApA  + (kt_) + ((kk_) << 5), &lds[wb + ((kk_) << 13) + (tid << 3)]); \
    gload_lds16(ApA2 + (kt_) + ((kk_) << 5), &lds[wb + ((kk_) << 13) + 4096 + (tid << 3)]); }
#define ST_B(kk_, kt_) { \
    gload_lds16(BpB  + (kt_) + ((kk_) << 5), &lds[wb + 16384 + ((kk_) << 13) + (tid << 3)]); \
    gload_lds16(BpB2 + (kt_) + ((kk_) << 5), &lds[wb + 16384 + ((kk_) << 13) + 4096 + (tid << 3)]); }
#define MM8(j_) { \
    acc[0][0] = __builtin_amdgcn_mfma_f32_32x32x16_bf16(a[0][j_], b[0][j_], acc[0][0], 0, 0, 0); \
    acc[0][1] = __builtin_amdgcn_mfma_f32_32x32x16_bf16(a[0][j_], b[1][j_], acc[0][1], 0, 0, 0); \
    acc[1][0] = __builtin_amdgcn_mfma_f32_32x32x16_bf16(a[1][j_], b[0][j_], acc[1][0], 0, 0, 0); \
    acc[1][1] = __builtin_amdgcn_mfma_f32_32x32x16_bf16(a[1][j_], b[1][j_], acc[1][1], 0, 0, 0); \
    acc[2][0] = __builtin_amdgcn_mfma_f32_32x32x16_bf16(a[2][j_], b[0][j_], acc[2][0], 0, 0, 0); \
    acc[2][1] = __builtin_amdgcn_mfma_f32_32x32x16_bf16(a[2][j_], b[1][j_], acc[2][1], 0, 0, 0); \
    acc[3][0] = __builtin_amdgcn_mfma_f32_32x32x16_bf16(a[3][j_], b[0][j_], acc[3][0], 0, 0, 0); \
    acc[3][1] = __builtin_amdgcn_mfma_f32_32x32x16_bf16(a[3][j_], b[1][j_], acc[3][1], 0, 0, 0); }
#define SB   __builtin_amdgcn_sched_barrier(0);
#define BAR  __builtin_amdgcn_s_barrier();
#define PRON __builtin_amdgcn_s_setprio(1);
#define PROFF __builtin_amdgcn_s_setprio(0);

#define PHASE(rb_, kk_, GATE, STG, kts_) { \
    if ((GATE) == 4)      { asm volatile("s_waitcnt vmcnt(4)" ::: "memory"); } \
    else if ((GATE) == 0) { asm volatile("s_waitcnt vmcnt(0)" ::: "memory"); } \
    BAR \
    const int pb = (rb_) + ((kk_) << 13); \
    b[0][0] = LD(pb + bbase + sj0);        b[0][1] = LD(pb + bbase + sj1); \
    b[1][0] = LD(pb + bbase + 1024 + sj0); b[1][1] = LD(pb + bbase + 1024 + sj1); \
    a[0][0] = LD(pb + abase + sj0);        a[0][1] = LD(pb + abase + sj1); \
    a[1][0] = LD(pb + abase + 1024 + sj0); a[1][1] = LD(pb + abase + 1024 + sj1); \
    a[2][0] = LD(pb + abase + 2048 + sj0); a[2][1] = LD(pb + abase + 2048 + sj1); \
    a[3][0] = LD(pb + abase + 3072 + sj0); a[3][1] = LD(pb + abase + 3072 + sj1); \
    if (STG) { ST_A(kk_, kts_); ST_B(kk_, kts_); } \
    SB PRON MM8(0) MM8(1) PROFF \
  }

  // prologue: stage tile 0 (per-thread order: A0,B0 [H0] then A1,B1 [H1])
  {
    const int wb = 0;
    ST_A(0, 0); ST_B(0, 0);
    ST_A(1, 0); ST_B(1, 0);
  }

  for (int t = 0; t < 31; ++t) {
    const int rb = (t & 1) << 15;
    const int wb = rb ^ 32768;
    const int kts = (t + 1) << 6;
    PHASE(rb, 0, 4, 1, kts)
    PHASE(rb, 1, 4, 1, kts)
  }
  {
    const int rb = (31 & 1) << 15;
    const int wb = 0; (void)wb;
    PHASE(rb, 0, 4, 0, 0)
    PHASE(rb, 1, 0, 0, 0)
  }

#undef PHASE
#undef PROFF
#undef PRON
#undef BAR
#undef SB
#undef MM8
#undef ST_B
#undef ST_A
#undef LD

  #pragma unroll
  for (int mf = 0; mf < 4; ++mf) {
    #pragma unroll
    for (int nf = 0; nf < 2; ++nf) {
      const int colw = (wc << 6) + (nf << 5) + l31;
      const float bv = bias[bnw + colw];
      #pragma unroll
      for (int reg = 0; reg < 16; ++reg) {
        const int row = bm + (wr << 7) + (mf << 5) + (reg & 3) + ((reg >> 2) << 3) + (l5 << 2);
        float v = acc[mf][nf][reg] + bv;
        if (QKV) { if (act) v = (v > 0.f) ? (v + 1.f) : __expf(v); }
        const size_t off = (size_t)row * ostr + bn + colw;
        if (OUT_BF16) ((unsigned short*)Cp)[off] = f2b(v);
        else          ((float*)Cp)[off] = v;
      }
    }
  }
}

// kv partials over 16 S-chunks (deterministic, no atomics). 1024 blocks -> 4/CU.
__global__ __launch_bounds__(256) void kv_partial(
    const unsigned short* __restrict__ kp, const unsigned short* __restrict__ vv,
    float* __restrict__ kvp, float* __restrict__ ksp)
{
  const int bh = blockIdx.x >> 4;
  const int chunk = blockIdx.x & 15;
  const int b = bh >> 4, h = bh & 15;
  const int tid = threadIdx.x;
  const int td = tid >> 4, te = tid & 15;

  __shared__ float kpl[32][128];
  __shared__ float vl[32][132];

  float acc[8][8] = {};
  float ks[8] = {};

  const size_t rowbase = (size_t)b * NS * QSTR + (size_t)h * HDIM;
  const int s0 = chunk * 256;

  for (int st = 0; st < 256; st += 32) {
    __syncthreads();
    #pragma unroll
    for (int i = 0; i < 2; ++i) {
      int idx = tid + (i << 8);
      int row = idx >> 4, q = idx & 15;
      size_t g = rowbase + (size_t)(s0 + st + row) * QSTR + (q << 3);
      u16x8 k8 = *(const u16x8*)(kp + g);
      u16x8 v8 = *(const u16x8*)(vv + g);
      float tk[8], tv[8];
      #pragma unroll
      for (int j = 0; j < 8; ++j) { tk[j] = b2f(k8[j]); tv[j] = b2f(v8[j]); }
      *(float4*)&kpl[row][(q << 3)]     = make_float4(tk[0], tk[1], tk[2], tk[3]);
      *(float4*)&kpl[row][(q << 3) + 4] = make_float4(tk[4], tk[5], tk[6], tk[7]);
      *(float4*)&vl[row][(q << 3)]      = make_float4(tv[0], tv[1], tv[2], tv[3]);
      *(float4*)&vl[row][(q << 3) + 4]  = make_float4(tv[4], tv[5], tv[6], tv[7]);
    }
    __syncthreads();
    #pragma unroll 4
    for (int s = 0; s < 32; ++s) {
      float kd[8], ve[8];
      *(float4*)&kd[0] = *(const float4*)&kpl[s][td << 3];
      *(float4*)&kd[4] = *(const float4*)&kpl[s][(td << 3) + 4];
      *(float4*)&ve[0] = *(const float4*)&vl[s][te << 3];
      *(float4*)&ve[4] = *(const float4*)&vl[s][(te << 3) + 4];
      if (te == 0) {
        #pragma unroll
        for (int i = 0; i < 8; ++i) ks[i] += kd[i];
      }
      #pragma unroll
      for (int i = 0; i < 8; ++i)
        #pragma unroll
        for (int j = 0; j < 8; ++j)
          acc[i][j] += kd[i] * ve[j];
    }
  }

  float* outp = kvp + ((size_t)(chunk * 64 + bh) << 14);
  #pragma unroll
  for (int j = 0; j < 8; ++j) {
    int e = (te << 3) + j;
    float r0[8];
    #pragma unroll
    for (int i = 0; i < 8; ++i) r0[i] = acc[i][j];
    *(float4*)&outp[(size_t)e * HDIM + (td << 3)]     = *(float4*)&r0[0];
    *(float4*)&outp[(size_t)e * HDIM + (td << 3) + 4] = *(float4*)&r0[4];
  }
  if (te == 0) {
    float* kso = ksp + ((size_t)(chunk * 64 + bh) << 7) + (td << 3);
    #pragma unroll
    for (int i = 0; i < 8; ++i) kso[i] = ks[i];
  }
}

__global__ __launch_bounds__(256) void kv_reduce(
    const float* __restrict__ kvp, float* __restrict__ kvT)
{
  int i = blockIdx.x * 256 + threadIdx.x;
  float s = 0.f;
  #pragma unroll
  for (int c = 0; c < 16; ++c) s += kvp[(size_t)c * (64 * 16384) + i];
  kvT[i] = s;
}

// attn[s,e] = (qp[s,:] . kvT[e,:]) / (z[s]+eps); qp = q cols of qkv, out -> v cols.
__global__ __launch_bounds__(256) void attn_ker(
    const unsigned short* __restrict__ qp, const float* __restrict__ kvT,
    const float* __restrict__ ksp, unsigned short* __restrict__ attn)
{
  const int bh = blockIdx.x >> 5, stile = blockIdx.x & 31;
  const int b = bh >> 4, h = bh & 15;
  const int tid = threadIdx.x;
  const int lane = tid & 63, w = tid >> 6;
  const int l15 = lane & 15, l4 = lane >> 4;

  __shared__ unsigned short Qs[128][136];
  __shared__ unsigned short Ks[128][136];
  __shared__ float ksl[128];
  __shared__ float zs[128];

  const size_t qbase = ((size_t)b * NS + (size_t)stile * 128) * QSTR + (size_t)h * HDIM;

  #pragma unroll
  for (int i = 0; i < 8; ++i) {
    int idx = tid + (i << 8);
    int row = idx >> 4, q = idx & 15;
    u16x8 v8 = *(const u16x8*)(qp + qbase + (size_t)row * QSTR + (q << 3));
    *(u16x8*)&Qs[row][q << 3] = v8;
  }
  const float* kvb = kvT + ((size_t)bh << 14);
  #pragma unroll
  for (int i = 0; i < 16; ++i) {
    int idx = tid + (i << 8);
    int row = idx >> 5, q = idx & 31;
    float4 v4 = *(const float4*)(kvb + (size_t)row * HDIM + (q << 2));
    ushort4 w4; w4.x = f2b(v4.x); w4.y = f2b(v4.y); w4.z = f2b(v4.z); w4.w = f2b(v4.w);
    *(ushort4*)&Ks[row][q << 2] = w4;
  }
  if (tid < 128) {
    float s = 0.f;
    #pragma unroll
    for (int c = 0; c < 16; ++c) s += ksp[((size_t)(c * 64 + bh) << 7) + tid];
    ksl[tid] = s;
  }
  __syncthreads();
  if (tid < 128) {
    float z = 0.f;
    #pragma unroll
    for (int dq = 0; dq < 16; ++dq) {
      u16x8 qv = *(const u16x8*)&Qs[tid][dq << 3];
      #pragma unroll
      for (int j = 0; j < 8; ++j) z += b2f(qv[j]) * ksl[(dq << 3) + j];
    }
    zs[tid] = 1.f / (z + EPSV);
  }
  __syncthreads();

  f32x4 acc[2][8] = {};
  #pragma unroll
  for (int kk = 0; kk < 4; ++kk) {
    s16x8 a[2], bb[8];
    #pragma unroll
    for (int mf = 0; mf < 2; ++mf)
      a[mf] = *(const s16x8*)&Qs[(w << 5) + (mf << 4) + l15][(kk << 5) + (l4 << 3)];
    #pragma unroll
    for (int nf = 0; nf < 8; ++nf)
      bb[nf] = *(const s16x8*)&Ks[(nf << 4) + l15][(kk << 5) + (l4 << 3)];
    #pragma unroll
    for (int mf = 0; mf < 2; ++mf)
      #pragma unroll
      for (int nf = 0; nf < 8; ++nf)
        acc[mf][nf] = __builtin_amdgcn_mfma_f32_16x16x32_bf16(a[mf], bb[nf], acc[mf][nf], 0, 0, 0);
  }

  #pragma unroll
  for (int mf = 0; mf < 2; ++mf) {
    #pragma unroll
    for (int r = 0; r < 4; ++r) {
      const int rl = (w << 5) + (mf << 4) + (l4 << 2) + r;
      const float zi = zs[rl];
      #pragma unroll
      for (int nf = 0; nf < 8; ++nf) {
        const int e = (nf << 4) + l15;
        attn[qbase + (size_t)rl * QSTR + e] = f2b(acc[mf][nf][r] * zi);
      }
    }
  }
}

extern "C" void kernel_launch(void* const* d_in, const int* in_sizes, int n_in,
                              void* d_out, int out_size, void* d_ws, size_t ws_size,
                              hipStream_t stream) {
  const float* hs = (const float*)d_in[0];
  const float* qw = (const float*)d_in[1];
  const float* qb = (const float*)d_in[2];
  const float* kw = (const float*)d_in[3];
  const float* kb = (const float*)d_in[4];
  const float* vw = (const float*)d_in[5];
  const float* vb = (const float*)d_in[6];
  const float* ow = (const float*)d_in[7];
  const float* ob = (const float*)d_in[8];

  char* w = (char*)d_ws;
  unsigned short* hsb = (unsigned short*)(w);                  // 64 MiB (dead after QKV gemm)
  unsigned short* qwb = (unsigned short*)(w + 67108864);       // 8 MiB each (q/k/v dead after QKV)
  unsigned short* kwb = (unsigned short*)(w + 75497472);
  unsigned short* vwb = (unsigned short*)(w + 83886080);
  unsigned short* owb = (unsigned short*)(w + 92274688);
  unsigned short* qkv = (unsigned short*)(w + 100663296);      // 192 MiB, row stride 6144
  // aliases over dead regions after QKV:
  float* kvp = (float*)(w);                                    // 64 MiB (16 chunks) over hsb
  float* ksp = (float*)(w + 67108864);                         // 512 KiB over qwb
  float* kvT = (float*)(w + 67108864 + 524288);                // 4 MiB over qwb

  convert_all<<<dim3(24576), dim3(256), 0, stream>>>(hs, qw, kw, vw, ow, hsb, qwb, kwb, vwb, owb);
  // QKV fused: M=16384, N=6144 (q|k|v columns), elu+1 on q,k. 64x24 = 1536 blocks.
  gemm256<1, 1><<<dim3(1536), dim3(512), 0, stream>>>(
      hsb, qwb, kwb, vwb, qb, kb, vb, qkv, 24, HIDC, QSTR);
  kv_partial<<<dim3(1024), dim3(256), 0, stream>>>(qkv + 2048, qkv + 4096, kvp, ksp);
  kv_reduce<<<dim3(4096), dim3(256), 0, stream>>>(kvp, kvT);
  attn_ker<<<dim3(2048), dim3(256), 0, stream>>>(qkv, kvT, ksp, qkv + 4096);
  // final: out = attn @ o_w^T + o_b, A = v-columns of qkv (astr=QSTR), fp32 out. 64x8 = 512 blocks.
  gemm256<0, 0><<<dim3(512), dim3(512), 0, stream>>>(
      qkv + 4096, owb, owb, owb, ob, ob, ob, d_out, 8, QSTR, HIDC);
}

// Round 13
// 765.547 us; speedup vs baseline: 1.0522x; 1.0077x over previous
//
#include <hip/hip_runtime.h>
#include <hip/hip_bf16.h>

#define HIDC 2048
#define NHEADS 16
#define HDIM 128
#define NB 4
#define NS 4096
#define NROWS (NB*NS)
#define QSTR 6144
#define EPSV 1e-6f

typedef __attribute__((ext_vector_type(8))) short s16x8;
typedef __attribute__((ext_vector_type(4))) float f32x4;
typedef __attribute__((ext_vector_type(16))) float f32x16;
typedef __attribute__((ext_vector_type(8))) unsigned short u16x8;

static __device__ __forceinline__ unsigned short f2b(float f) {
  unsigned int u = __float_as_uint(f);
  u += 0x7fffu + ((u >> 16) & 1u);
  return (unsigned short)(u >> 16);
}
static __device__ __forceinline__ float b2f(unsigned short h) {
  return __uint_as_float(((unsigned int)h) << 16);
}

static __device__ __forceinline__ void gload_lds16(const unsigned short* g, unsigned short* l) {
  __builtin_amdgcn_global_load_lds(
      (const __attribute__((address_space(1))) void*)g,
      (__attribute__((address_space(3))) void*)l, 16, 0, 0);
}

// fp32 -> bf16 conversion for hs (16384 blocks) + 4 weights (2048 blocks each)
__global__ __launch_bounds__(256) void convert_all(
    const float* __restrict__ hs, const float* __restrict__ qw,
    const float* __restrict__ kw, const float* __restrict__ vw,
    const float* __restrict__ ow,
    unsigned short* __restrict__ hsb, unsigned short* __restrict__ qwb,
    unsigned short* __restrict__ kwb, unsigned short* __restrict__ vwb,
    unsigned short* __restrict__ owb)
{
  int bid = blockIdx.x;
  const float* src; unsigned short* dst; size_t base;
  if (bid < 16384) { src = hs; dst = hsb; base = (size_t)bid << 11; }
  else {
    int t = bid - 16384; int wsel = t >> 11; int wb = t & 2047;
    src = wsel == 0 ? qw : wsel == 1 ? kw : wsel == 2 ? vw : ow;
    dst = wsel == 0 ? qwb : wsel == 1 ? kwb : wsel == 2 ? vwb : owb;
    base = (size_t)wb << 11;
  }
  size_t i = base + ((size_t)threadIdx.x << 3);
  float4 a = *(const float4*)(src + i);
  float4 b = *(const float4*)(src + i + 4);
  u16x8 o;
  o[0] = f2b(a.x); o[1] = f2b(a.y); o[2] = f2b(a.z); o[3] = f2b(a.w);
  o[4] = f2b(b.x); o[5] = f2b(b.y); o[6] = f2b(b.z); o[7] = f2b(b.w);
  *(u16x8*)(dst + i) = o;
}

// 256x256-tile bf16 GEMM on mfma_f32_32x32x16_bf16, 8 waves (2Mx4N, wave-tile
// 128x64 = 4x2 frags), BK=64, ring-2 LDS buffers, 2 phases/tile.
// READ-ORDER PIPELINING (this round's change): phase reads are grouped
// j0-block (6 reads: operands of MM8(0)) -> stage -> j1-block (6 reads:
// operands of MM8(1)). Counted lgkm waits then let MM8(0) start after only
// the j0 drain, and the j1 reads drain UNDER MM8(0)'s MFMA epoch.
// Swizzle: slot' = s ^ ((row>>3)&3); staging pre-swizzles global col.
// C/D: col=l&31, row=(reg&3)+8*(reg>>2)+4*(l>>5)  [m74/m101-verified].
template<int QKV, int OUT_BF16>
__global__ __launch_bounds__(512, 1) void gemm256(
    const unsigned short* __restrict__ A,
    const unsigned short* __restrict__ B0,
    const unsigned short* __restrict__ B1,
    const unsigned short* __restrict__ B2,
    const float* __restrict__ bias0,
    const float* __restrict__ bias1,
    const float* __restrict__ bias2,
    void* __restrict__ Cp,
    int ntile, int astr, int ostr)
{
  __shared__ unsigned short lds[65536];   // 2 buf x [A:16384][B:16384]
  const int tid = threadIdx.x;
  const int lane = tid & 63, wid = tid >> 6;
  const int wr = wid >> 2, wc = wid & 3;
  const int l31 = lane & 31, l5 = lane >> 5;

  // bijective XCD swizzle (grid % 8 == 0) + L2 chunking: 4 bm x all bn
  const int cpx = (int)gridDim.x >> 3;
  const int bidx = (int)blockIdx.x;
  const int wg = (bidx & 7) * cpx + (bidx >> 3);
  const int csz = ntile << 2;
  const int chunk = wg / csz;
  const int tt = wg % csz;
  const int bm = ((chunk << 2) + (tt & 3)) << 8;
  const int bn = (tt >> 2) << 8;

  const unsigned short* Bp = B0;
  const float* bias = bias0;
  bool act = false;
  int bnw = bn;
  if (QKV) {
    int seg = bn >> 11;
    Bp = seg == 0 ? B0 : (seg == 1 ? B1 : B2);
    bias = seg == 0 ? bias0 : (seg == 1 ? bias1 : bias2);
    act = seg < 2;
    bnw = bn & 2047;
  }

  // staging: half-tile = one 256x32 panel of A + one of B (16 KB each).
  const int r0 = tid >> 2;
  const int s0 = tid & 3;
  const int scol = ((s0 ^ ((r0 >> 3) & 3)) << 3);
  const unsigned short* ApA  = A  + (size_t)(bm  + r0) * astr + scol;
  const unsigned short* ApA2 = ApA + (size_t)128 * astr;
  const unsigned short* BpB  = Bp + (size_t)(bnw + r0) * HIDC + scol;
  const unsigned short* BpB2 = BpB + (size_t)128 * HIDC;

  // fragment read addressing: row r = base + l31, slot s_nat = 2j + l5,
  // swizzled s' = s_nat ^ ((l31>>3)&3).
  const int xr = (l31 >> 3) & 3;
  const int sj0 = ((l5 ^ xr) << 3);
  const int sj1 = (((2 + l5) ^ xr) << 3);
  const int abase = ((wr << 7) + l31) * 32;           // + mf*1024 + kk*8192 + sj
  const int bbase = 16384 + ((wc << 6) + l31) * 32;   // + nf*1024 + kk*8192 + sj

  f32x16 acc[4][2] = {};
  s16x8 a[4][2], b[2][2];

#define LD(off_) (*(const s16x8*)&lds[off_])
#define ST_A(kk_, kt_) { \
    gload_lds16(ApA  + (kt_) + ((kk_) << 5), &lds[wb + ((kk_) << 13) + (tid << 3)]); \
    gload_lds16(ApA2 + (kt_) + ((kk_) << 5), &lds[wb + ((kk_) << 13) + 4096 + (tid << 3)]); }
#define ST_B(kk_, kt_) { \
    gload_lds16(BpB  + (kt_) + ((kk_) << 5), &lds[wb + 16384 + ((kk_) << 13) + (tid << 3)]); \
    gload_lds16(BpB2 + (kt_) + ((kk_) << 5), &lds[wb + 16384 + ((kk_) << 13) + 4096 + (tid << 3)]); }
#define MM8(j_) { \
    acc[0][0] = __builtin_amdgcn_mfma_f32_32x32x16_bf16(a[0][j_], b[0][j_], acc[0][0], 0, 0, 0); \
    acc[0][1] = __builtin_amdgcn_mfma_f32_32x32x16_bf16(a[0][j_], b[1][j_], acc[0][1], 0, 0, 0); \
    acc[1][0] = __builtin_amdgcn_mfma_f32_32x32x16_bf16(a[1][j_], b[0][j_], acc[1][0], 0, 0, 0); \
    acc[1][1] = __builtin_amdgcn_mfma_f32_32x32x16_bf16(a[1][j_], b[1][j_], acc[1][1], 0, 0, 0); \
    acc[2][0] = __builtin_amdgcn_mfma_f32_32x32x16_bf16(a[2][j_], b[0][j_], acc[2][0], 0, 0, 0); \
    acc[2][1] = __builtin_amdgcn_mfma_f32_32x32x16_bf16(a[2][j_], b[1][j_], acc[2][1], 0, 0, 0); \
    acc[3][0] = __builtin_amdgcn_mfma_f32_32x32x16_bf16(a[3][j_], b[0][j_], acc[3][0], 0, 0, 0); \
    acc[3][1] = __builtin_amdgcn_mfma_f32_32x32x16_bf16(a[3][j_], b[1][j_], acc[3][1], 0, 0, 0); }
#define SB   __builtin_amdgcn_sched_barrier(0);
#define BAR  __builtin_amdgcn_s_barrier();
#define PRON __builtin_amdgcn_s_setprio(1);
#define PROFF __builtin_amdgcn_s_setprio(0);

#define PHASE(rb_, kk_, GATE, STG, kts_) { \
    if ((GATE) == 4)      { asm volatile("s_waitcnt vmcnt(4)" ::: "memory"); } \
    else if ((GATE) == 0) { asm volatile("s_waitcnt vmcnt(0)" ::: "memory"); } \
    BAR \
    const int pb = (rb_) + ((kk_) << 13); \
    /* j0 block: MM8(0)'s operands, first in the LDS queue */ \
    b[0][0] = LD(pb + bbase + sj0); \
    b[1][0] = LD(pb + bbase + 1024 + sj0); \
    a[0][0] = LD(pb + abase + sj0); \
    a[1][0] = LD(pb + abase + 1024 + sj0); \
    a[2][0] = LD(pb + abase + 2048 + sj0); \
    a[3][0] = LD(pb + abase + 3072 + sj0); \
    if (STG) { ST_A(kk_, kts_); ST_B(kk_, kts_); } \
    /* j1 block: MM8(1)'s operands, drain under MM8(0)'s MFMA epoch */ \
    b[0][1] = LD(pb + bbase + sj1); \
    b[1][1] = LD(pb + bbase + 1024 + sj1); \
    a[0][1] = LD(pb + abase + sj1); \
    a[1][1] = LD(pb + abase + 1024 + sj1); \
    a[2][1] = LD(pb + abase + 2048 + sj1); \
    a[3][1] = LD(pb + abase + 3072 + sj1); \
    SB PRON MM8(0) MM8(1) PROFF \
  }

  // prologue: stage tile 0 (per-thread order: A0,B0 [H0] then A1,B1 [H1])
  {
    const int wb = 0;
    ST_A(0, 0); ST_B(0, 0);
    ST_A(1, 0); ST_B(1, 0);
  }

  for (int t = 0; t < 31; ++t) {
    const int rb = (t & 1) << 15;
    const int wb = rb ^ 32768;
    const int kts = (t + 1) << 6;
    PHASE(rb, 0, 4, 1, kts)
    PHASE(rb, 1, 4, 1, kts)
  }
  {
    const int rb = (31 & 1) << 15;
    const int wb = 0; (void)wb;
    PHASE(rb, 0, 4, 0, 0)
    PHASE(rb, 1, 0, 0, 0)
  }

#undef PHASE
#undef PROFF
#undef PRON
#undef BAR
#undef SB
#undef MM8
#undef ST_B
#undef ST_A
#undef LD

  #pragma unroll
  for (int mf = 0; mf < 4; ++mf) {
    #pragma unroll
    for (int nf = 0; nf < 2; ++nf) {
      const int colw = (wc << 6) + (nf << 5) + l31;
      const float bv = bias[bnw + colw];
      #pragma unroll
      for (int reg = 0; reg < 16; ++reg) {
        const int row = bm + (wr << 7) + (mf << 5) + (reg & 3) + ((reg >> 2) << 3) + (l5 << 2);
        float v = acc[mf][nf][reg] + bv;
        if (QKV) { if (act) v = (v > 0.f) ? (v + 1.f) : __expf(v); }
        const size_t off = (size_t)row * ostr + bn + colw;
        if (OUT_BF16) ((unsigned short*)Cp)[off] = f2b(v);
        else          ((float*)Cp)[off] = v;
      }
    }
  }
}

// kv partials over 16 S-chunks (deterministic, no atomics). 1024 blocks -> 4/CU.
__global__ __launch_bounds__(256) void kv_partial(
    const unsigned short* __restrict__ kp, const unsigned short* __restrict__ vv,
    float* __restrict__ kvp, float* __restrict__ ksp)
{
  const int bh = blockIdx.x >> 4;
  const int chunk = blockIdx.x & 15;
  const int b = bh >> 4, h = bh & 15;
  const int tid = threadIdx.x;
  const int td = tid >> 4, te = tid & 15;

  __shared__ float kpl[32][128];
  __shared__ float vl[32][132];

  float acc[8][8] = {};
  float ks[8] = {};

  const size_t rowbase = (size_t)b * NS * QSTR + (size_t)h * HDIM;
  const int s0 = chunk * 256;

  for (int st = 0; st < 256; st += 32) {
    __syncthreads();
    #pragma unroll
    for (int i = 0; i < 2; ++i) {
      int idx = tid + (i << 8);
      int row = idx >> 4, q = idx & 15;
      size_t g = rowbase + (size_t)(s0 + st + row) * QSTR + (q << 3);
      u16x8 k8 = *(const u16x8*)(kp + g);
      u16x8 v8 = *(const u16x8*)(vv + g);
      float tk[8], tv[8];
      #pragma unroll
      for (int j = 0; j < 8; ++j) { tk[j] = b2f(k8[j]); tv[j] = b2f(v8[j]); }
      *(float4*)&kpl[row][(q << 3)]     = make_float4(tk[0], tk[1], tk[2], tk[3]);
      *(float4*)&kpl[row][(q << 3) + 4] = make_float4(tk[4], tk[5], tk[6], tk[7]);
      *(float4*)&vl[row][(q << 3)]      = make_float4(tv[0], tv[1], tv[2], tv[3]);
      *(float4*)&vl[row][(q << 3) + 4]  = make_float4(tv[4], tv[5], tv[6], tv[7]);
    }
    __syncthreads();
    #pragma unroll 4
    for (int s = 0; s < 32; ++s) {
      float kd[8], ve[8];
      *(float4*)&kd[0] = *(const float4*)&kpl[s][td << 3];
      *(float4*)&kd[4] = *(const float4*)&kpl[s][(td << 3) + 4];
      *(float4*)&ve[0] = *(const float4*)&vl[s][te << 3];
      *(float4*)&ve[4] = *(const float4*)&vl[s][(te << 3) + 4];
      if (te == 0) {
        #pragma unroll
        for (int i = 0; i < 8; ++i) ks[i] += kd[i];
      }
      #pragma unroll
      for (int i = 0; i < 8; ++i)
        #pragma unroll
        for (int j = 0; j < 8; ++j)
          acc[i][j] += kd[i] * ve[j];
    }
  }

  float* outp = kvp + ((size_t)(chunk * 64 + bh) << 14);
  #pragma unroll
  for (int j = 0; j < 8; ++j) {
    int e = (te << 3) + j;
    float r0[8];
    #pragma unroll
    for (int i = 0; i < 8; ++i) r0[i] = acc[i][j];
    *(float4*)&outp[(size_t)e * HDIM + (td << 3)]     = *(float4*)&r0[0];
    *(float4*)&outp[(size_t)e * HDIM + (td << 3) + 4] = *(float4*)&r0[4];
  }
  if (te == 0) {
    float* kso = ksp + ((size_t)(chunk * 64 + bh) << 7) + (td << 3);
    #pragma unroll
    for (int i = 0; i < 8; ++i) kso[i] = ks[i];
  }
}

__global__ __launch_bounds__(256) void kv_reduce(
    const float* __restrict__ kvp, float* __restrict__ kvT)
{
  int i = blockIdx.x * 256 + threadIdx.x;
  float s = 0.f;
  #pragma unroll
  for (int c = 0; c < 16; ++c) s += kvp[(size_t)c * (64 * 16384) + i];
  kvT[i] = s;
}

// attn[s,e] = (qp[s,:] . kvT[e,:]) / (z[s]+eps); qp = q cols of qkv, out -> v cols.
__global__ __launch_bounds__(256) void attn_ker(
    const unsigned short* __restrict__ qp, const float* __restrict__ kvT,
    const float* __restrict__ ksp, unsigned short* __restrict__ attn)
{
  const int bh = blockIdx.x >> 5, stile = blockIdx.x & 31;
  const int b = bh >> 4, h = bh & 15;
  const int tid = threadIdx.x;
  const int lane = tid & 63, w = tid >> 6;
  const int l15 = lane & 15, l4 = lane >> 4;

  __shared__ unsigned short Qs[128][136];
  __shared__ unsigned short Ks[128][136];
  __shared__ float ksl[128];
  __shared__ float zs[128];

  const size_t qbase = ((size_t)b * NS + (size_t)stile * 128) * QSTR + (size_t)h * HDIM;

  #pragma unroll
  for (int i = 0; i < 8; ++i) {
    int idx = tid + (i << 8);
    int row = idx >> 4, q = idx & 15;
    u16x8 v8 = *(const u16x8*)(qp + qbase + (size_t)row * QSTR + (q << 3));
    *(u16x8*)&Qs[row][q << 3] = v8;
  }
  const float* kvb = kvT + ((size_t)bh << 14);
  #pragma unroll
  for (int i = 0; i < 16; ++i) {
    int idx = tid + (i << 8);
    int row = idx >> 5, q = idx & 31;
    float4 v4 = *(const float4*)(kvb + (size_t)row * HDIM + (q << 2));
    ushort4 w4; w4.x = f2b(v4.x); w4.y = f2b(v4.y); w4.z = f2b(v4.z); w4.w = f2b(v4.w);
    *(ushort4*)&Ks[row][q << 2] = w4;
  }
  if (tid < 128) {
    float s = 0.f;
    #pragma unroll
    for (int c = 0; c < 16; ++c) s += ksp[((size_t)(c * 64 + bh) << 7) + tid];
    ksl[tid] = s;
  }
  __syncthreads();
  if (tid < 128) {
    float z = 0.f;
    #pragma unroll
    for (int dq = 0; dq < 16; ++dq) {
      u16x8 qv = *(const u16x8*)&Qs[tid][dq << 3];
      #pragma unroll
      for (int j = 0; j < 8; ++j) z += b2f(qv[j]) * ksl[(dq << 3) + j];
    }
    zs[tid] = 1.f / (z + EPSV);
  }
  __syncthreads();

  f32x4 acc[2][8] = {};
  #pragma unroll
  for (int kk = 0; kk < 4; ++kk) {
    s16x8 a[2], bb[8];
    #pragma unroll
    for (int mf = 0; mf < 2; ++mf)
      a[mf] = *(const s16x8*)&Qs[(w << 5) + (mf << 4) + l15][(kk << 5) + (l4 << 3)];
    #pragma unroll
    for (int nf = 0; nf < 8; ++nf)
      bb[nf] = *(const s16x8*)&Ks[(nf << 4) + l15][(kk << 5) + (l4 << 3)];
    #pragma unroll
    for (int mf = 0; mf < 2; ++mf)
      #pragma unroll
      for (int nf = 0; nf < 8; ++nf)
        acc[mf][nf] = __builtin_amdgcn_mfma_f32_16x16x32_bf16(a[mf], bb[nf], acc[mf][nf], 0, 0, 0);
  }

  #pragma unroll
  for (int mf = 0; mf < 2; ++mf) {
    #pragma unroll
    for (int r = 0; r < 4; ++r) {
      const int rl = (w << 5) + (mf << 4) + (l4 << 2) + r;
      const float zi = zs[rl];
      #pragma unroll
      for (int nf = 0; nf < 8; ++nf) {
        const int e = (nf << 4) + l15;
        attn[qbase + (size_t)rl * QSTR + e] = f2b(acc[mf][nf][r] * zi);
      }
    }
  }
}

extern "C" void kernel_launch(void* const* d_in, const int* in_sizes, int n_in,
                              void* d_out, int out_size, void* d_ws, size_t ws_size,
                              hipStream_t stream) {
  const float* hs = (const float*)d_in[0];
  const float* qw = (const float*)d_in[1];
  const float* qb = (const float*)d_in[2];
  const float* kw = (const float*)d_in[3];
  const float* kb = (const float*)d_in[4];
  const float* vw = (const float*)d_in[5];
  const float* vb = (const float*)d_in[6];
  const float* ow = (const float*)d_in[7];
  const float* ob = (const float*)d_in[8];

  char* w = (char*)d_ws;
  unsigned short* hsb = (unsigned short*)(w);                  // 64 MiB (dead after QKV gemm)
  unsigned short* qwb = (unsigned short*)(w + 67108864);       // 8 MiB each (q/k/v dead after QKV)
  unsigned short* kwb = (unsigned short*)(w + 75497472);
  unsigned short* vwb = (unsigned short*)(w + 83886080);
  unsigned short* owb = (unsigned short*)(w + 92274688);
  unsigned short* qkv = (unsigned short*)(w + 100663296);      // 192 MiB, row stride 6144
  // aliases over dead regions after QKV:
  float* kvp = (float*)(w);                                    // 64 MiB (16 chunks) over hsb
  float* ksp = (float*)(w + 67108864);                         // 512 KiB over qwb
  float* kvT = (float*)(w + 67108864 + 524288);                // 4 MiB over qwb

  convert_all<<<dim3(24576), dim3(256), 0, stream>>>(hs, qw, kw, vw, ow, hsb, qwb, kwb, vwb, owb);
  // QKV fused: M=16384, N=6144 (q|k|v columns), elu+1 on q,k. 64x24 = 1536 blocks.
  gemm256<1, 1><<<dim3(1536), dim3(512), 0, stream>>>(
      hsb, qwb, kwb, vwb, qb, kb, vb, qkv, 24, HIDC, QSTR);
  kv_partial<<<dim3(1024), dim3(256), 0, stream>>>(qkv + 2048, qkv + 4096, kvp, ksp);
  kv_reduce<<<dim3(4096), dim3(256), 0, stream>>>(kvp, kvT);
  attn_ker<<<dim3(2048), dim3(256), 0, stream>>>(qkv, kvT, ksp, qkv + 4096);
  // final: out = attn @ o_w^T + o_b, A = v-columns of qkv (astr=QSTR), fp32 out. 64x8 = 512 blocks.
  gemm256<0, 0><<<dim3(512), dim3(512), 0, stream>>>(
      qkv + 4096, owb, owb, owb, ob, ob, ob, d_out, 8, QSTR, HIDC);
}